// Round 15
// baseline (66.124 us; speedup 1.0000x reference)
//
#include <hip/hip_runtime.h>

typedef __attribute__((ext_vector_type(8))) short bf16x8;
typedef __attribute__((ext_vector_type(16))) float f32x16;

#define LN 8192
#define SA_ROWB 4240          // bytes/shifted-copy row; 4240/16=265 ≡ 1 (mod 8) → bank spread
#define SB_OFF  33920         // B buffer starts after 8 A-rows (8*4240)
#define SMEM_BYTES 65536

__device__ __forceinline__ unsigned short f2bf(float f) {
    unsigned int u = __float_as_uint(f);
    u += 0x7fffu + ((u >> 16) & 1u);
    return (unsigned short)(u >> 16);
}
__device__ __forceinline__ float lrelu(float v) { return v > 0.f ? v : 0.01f * v; }
__device__ __forceinline__ float gldx(const float* p, int i) { return (i >= 0 && i < LN) ? p[i] : 0.f; }

__device__ __forceinline__ void dot8bf(uint4 q, const float* nl, float& acc) {
    acc += __uint_as_float(q.x << 16)          * nl[0];
    acc += __uint_as_float(q.x & 0xffff0000u)  * nl[1];
    acc += __uint_as_float(q.y << 16)          * nl[2];
    acc += __uint_as_float(q.y & 0xffff0000u)  * nl[3];
    acc += __uint_as_float(q.z << 16)          * nl[4];
    acc += __uint_as_float(q.z & 0xffff0000u)  * nl[5];
    acc += __uint_as_float(q.w << 16)          * nl[6];
    acc += __uint_as_float(q.w & 0xffff0000u)  * nl[7];
}
__device__ __forceinline__ uint4 pack8(float4 a, float4 b) {
    uint4 pk;
    pk.x = (unsigned)f2bf(a.x) | ((unsigned)f2bf(a.y) << 16);
    pk.y = (unsigned)f2bf(a.z) | ((unsigned)f2bf(a.w) << 16);
    pk.z = (unsigned)f2bf(b.x) | ((unsigned)f2bf(b.y) << 16);
    pk.w = (unsigned)f2bf(b.z) | ((unsigned)f2bf(b.w) << 16);
    return pk;
}

// Fixed-NT batched ACF region: per iteration, 2 A + 2*NT B loads (independent,
// batched) then 2*NT MFMAs. Per-accumulator MFMA order = mq ascending (bit-identical).
template<int NT>
__device__ __forceinline__ void acf_region(
    const unsigned char* smem, int aoff_lane, int c0, int g, int jj, int gp,
    int m0, int m1, f32x16 (&acc)[4])
{
    const unsigned char* ap = smem + aoff_lane + 32 * (m0 - c0);
    int Sb = 128 * g + 2 * m0 + 4 * jj + gp;
    for (int mq = m0; mq < m1; mq += 2) {
        bf16x8 A[2], B[NT][2];
        #pragma unroll
        for (int u = 0; u < 2; ++u) A[u] = *(const bf16x8*)(ap + 32 * u);
        #pragma unroll
        for (int t = 0; t < NT; ++t) {
            #pragma unroll
            for (int u = 0; u < 2; ++u) {
                const int s = Sb + 2 * u + 256 * t;
                B[t][u] = *(const bf16x8*)(smem + SB_OFF + ((s ^ ((s >> 3) & 7)) << 4));
            }
        }
        #pragma unroll
        for (int u = 0; u < 2; ++u)
            #pragma unroll
            for (int t = 0; t < NT; ++t)
                acc[t] = __builtin_amdgcn_mfma_f32_32x32x16_bf16(A[u], B[t][u], acc[t], 0, 0, 0);
        ap += 64; Sb += 4;
    }
}

// K0: reformat W1,W2 -> k-major packed bf16 (round-13 verified, unchanged)
__global__ __launch_bounds__(256)
void conv_kernel(const float* __restrict__ W1, const float* __restrict__ W2,
                 uint4* __restrict__ W1p, uint4* __restrict__ W2p)
{
    const int b = blockIdx.x, t = threadIdx.x;
    if (b < 256) {
        const int g = b * 256 + t;
        const int n = g >> 7, kqq = g & 127;
        const float4* src = (const float4*)(W1 + (size_t)n * 1024 + 8 * kqq);
        W1p[kqq * 512 + n] = pack8(src[0], src[1]);
    } else {
        const int g = (b - 256) * 256 + t;
        const int n = g >> 6, kqq = g & 63;
        const float4* src = (const float4*)(W2 + (size_t)n * 512 + 8 * kqq);
        W2p[kqq * 256 + n] = pack8(src[0], src[1]);
    }
}

// K1: fused ACF + row-local MLP. Quad A-sharing (round-14 verified decomposition)
// with round-13-style batched loads (fixed-NT regions, no in-loop branches).
__global__ __launch_bounds__(1024)
void fused_kernel(const float* __restrict__ x,
                  const uint4* __restrict__ W1p, const float* __restrict__ b1,
                  const uint4* __restrict__ W2p, const float* __restrict__ b2,
                  const float* __restrict__ W3, const float* __restrict__ b3,
                  float* __restrict__ out)
{
    __shared__ __align__(16) unsigned char smem[SMEM_BYTES];
    __shared__ float red[16];

    const int tid  = threadIdx.x;
    const int row  = blockIdx.x;
    const int lane = tid & 63;
    const int wv   = tid >> 6;
    const float* xr = x + (size_t)row * LN;

    // ---------------- phase A: ACF ----------------
    const int jj = lane & 31;
    const int gp = lane >> 5;
    const int dd = lane & 7;
    const int hh = (lane >> 3) & 3;
    const int aoff_lane = dd * SA_ROWB + 64 + 16 * gp - 16 * hh;

    const int g = wv & 1;          // quad: tiles {g, g+2, g+4, g+6}
    const int w = wv >> 1;         // 0..7 within quad

    // stage B: padded bf16 v, 16B-slot XOR swizzle (identical)
    for (int s = tid; s < 1156; s += 1024) {
        const int e0 = s * 8;
        float4 fa, fb;
        if (e0 + 7 < LN) {
            fa = *(const float4*)(xr + e0);
            fb = *(const float4*)(xr + e0 + 4);
        } else {
            fa = make_float4(gldx(xr,e0),   gldx(xr,e0+1), gldx(xr,e0+2), gldx(xr,e0+3));
            fb = make_float4(gldx(xr,e0+4), gldx(xr,e0+5), gldx(xr,e0+6), gldx(xr,e0+7));
        }
        uint4 pk = pack8(fa, fb);
        const int ph = s ^ ((s >> 3) & 7);
        *(uint4*)(smem + SB_OFF + ph * 16) = pk;
    }

    f32x16 acc[4] = {{}, {}, {}, {}};

    for (int ch = 0; ch < 4; ++ch) {
        const int tc = ch << 11;
        __syncthreads();
        // stage A: copy_d[p4] = v[tc + p4 - 32 - d] (identical)
        if (tid < 528) {
            const int base = tc + 4 * tid - 40;
            float4 fa, fb, fc;
            if (base >= 0 && base + 11 < LN) {
                fa = *(const float4*)(xr + base);
                fb = *(const float4*)(xr + base + 4);
                fc = *(const float4*)(xr + base + 8);
            } else {
                fa = make_float4(gldx(xr,base),   gldx(xr,base+1), gldx(xr,base+2),  gldx(xr,base+3));
                fb = make_float4(gldx(xr,base+4), gldx(xr,base+5), gldx(xr,base+6),  gldx(xr,base+7));
                fc = make_float4(gldx(xr,base+8), gldx(xr,base+9), gldx(xr,base+10), gldx(xr,base+11));
            }
            unsigned short us[12];
            us[0]=f2bf(fa.x); us[1]=f2bf(fa.y); us[2]=f2bf(fa.z);  us[3]=f2bf(fa.w);
            us[4]=f2bf(fb.x); us[5]=f2bf(fb.y); us[6]=f2bf(fb.z);  us[7]=f2bf(fb.w);
            us[8]=f2bf(fc.x); us[9]=f2bf(fc.y); us[10]=f2bf(fc.z); us[11]=f2bf(fc.w);
            #pragma unroll
            for (int d = 0; d < 8; ++d) {
                unsigned long long pk = (unsigned long long)us[8-d]
                                      | ((unsigned long long)us[9-d]  << 16)
                                      | ((unsigned long long)us[10-d] << 32)
                                      | ((unsigned long long)us[11-d] << 48);
                *(unsigned long long*)(smem + d * SA_ROWB + 8 * tid) = pk;
            }
        }
        __syncthreads();

        const int c0 = ch * 128;
        // region table (round-14 verified): g0: [c0+16w,+16) x nt=4-ch;
        // g1: [c0+8w,+8) x nt=4-ch and [c0+64+8w,+8) x nt=3-ch (skip when 0).
        const int nta = 4 - ch;
        if (g == 0) {
            const int m0 = c0 + 16 * w, m1 = m0 + 16;
            switch (nta) {
                case 4: acf_region<4>(smem, aoff_lane, c0, g, jj, gp, m0, m1, acc); break;
                case 3: acf_region<3>(smem, aoff_lane, c0, g, jj, gp, m0, m1, acc); break;
                case 2: acf_region<2>(smem, aoff_lane, c0, g, jj, gp, m0, m1, acc); break;
                default: acf_region<1>(smem, aoff_lane, c0, g, jj, gp, m0, m1, acc); break;
            }
        } else {
            const int m0 = c0 + 8 * w, m1 = m0 + 8;
            switch (nta) {
                case 4: acf_region<4>(smem, aoff_lane, c0, g, jj, gp, m0, m1, acc); break;
                case 3: acf_region<3>(smem, aoff_lane, c0, g, jj, gp, m0, m1, acc); break;
                case 2: acf_region<2>(smem, aoff_lane, c0, g, jj, gp, m0, m1, acc); break;
                default: acf_region<1>(smem, aoff_lane, c0, g, jj, gp, m0, m1, acc); break;
            }
            const int ntb = 3 - ch;
            if (ntb > 0) {
                const int n0 = c0 + 64 + 8 * w, n1 = n0 + 8;
                switch (ntb) {
                    case 3: acf_region<3>(smem, aoff_lane, c0, g, jj, gp, n0, n1, acc); break;
                    case 2: acf_region<2>(smem, aoff_lane, c0, g, jj, gp, n0, n1, acc); break;
                    default: acf_region<1>(smem, aoff_lane, c0, g, jj, gp, n0, n1, acc); break;
                }
            }
        }
    }

    __syncthreads();   // all MFMA reads done; overlay staging with partial buffer

    // partial buffer: [T][slot][j(32)][i(32 f32, 16B-blocks XOR-swizzled by j&7)]
    auto pwrite = [&](int T, int s, const f32x16& a, bool add) {
        unsigned char* bp = smem + (T * 2 + s) * 4096 + jj * 128;
        #pragma unroll
        for (int rq = 0; rq < 4; ++rq) {
            const int bi = (2 * rq + gp) ^ (jj & 7);
            float4 wt = make_float4(a[4*rq], a[4*rq+1], a[4*rq+2], a[4*rq+3]);
            float4* pp = (float4*)(bp + bi * 16);
            if (add) { float4 o = *pp; wt.x += o.x; wt.y += o.y; wt.z += o.z; wt.w += o.w; }
            *pp = wt;
        }
    };
    // 4 RMW phases (round-14 verified): slot = w&1; phase = w>>1
    {
        const int slot  = w & 1;
        const int phase = w >> 1;
        #pragma unroll
        for (int pi = 0; pi < 4; ++pi) {
            if (phase == pi) {
                const bool add = (pi > 0);
                pwrite(g,     slot, acc[0], add);
                pwrite(g + 2, slot, acc[1], add);
                pwrite(g + 4, slot, acc[2], add);
                pwrite(g + 6, slot, acc[3], add);
            }
            __syncthreads();
        }
    }

    // LDS overlay for MLP phases
    float* nrm = (float*)smem;                   // [0, 4096)
    float* h1  = (float*)(smem + 4096);          // [4096, 6144)
    float* h2  = (float*)(smem + 6144);          // [6144, 7168)
    float* ph  = (float*)(smem + 7168);          // [7168, 9216)
    float* pe  = (float*)(smem + 9216);          // [9216, 12288)

    // ---- phase C: pool8 + rowmax + normalize -> nrm (identical) ----
    {
        const int T  = tid >> 7;
        const int j2 = (tid >> 2) & 31;
        const int rq = tid & 3;
        const unsigned char* b0 = smem + (T * 2) * 4096 + j2 * 128;
        const int biA = (2 * rq)     ^ (j2 & 7);
        const int biB = (2 * rq + 1) ^ (j2 & 7);
        float4 s0a = *(const float4*)(b0 + biA * 16);
        float4 s0b = *(const float4*)(b0 + biB * 16);
        float4 s1a = *(const float4*)(b0 + 4096 + biA * 16);
        float4 s1b = *(const float4*)(b0 + 4096 + biB * 16);
        float v0 = s0a.x + s1a.x, v1 = s0a.y + s1a.y, v2 = s0a.z + s1a.z, v3 = s0a.w + s1a.w;
        float v4 = s0b.x + s1b.x, v5 = s0b.y + s1b.y, v6 = s0b.z + s1b.z, v7 = s0b.w + s1b.w;
        float m = fmaxf(fmaxf(fmaxf(v0, v1), fmaxf(v2, v3)), fmaxf(fmaxf(v4, v5), fmaxf(v6, v7)));

        float mx = m;
        for (int off = 32; off > 0; off >>= 1) mx = fmaxf(mx, __shfl_xor(mx, off));
        if (lane == 0) red[wv] = mx;
        __syncthreads();
        float pmax = red[0];
        #pragma unroll
        for (int k = 1; k < 16; ++k) pmax = fmaxf(pmax, red[k]);
        nrm[tid] = m * (1.0f / pmax);
    }
    __syncthreads();

    // ---- phase D: layer 1, neuron-per-lane (round-13 verified) ----
    {
        const int n  = tid & 511;
        const int kh = tid >> 9;
        const float4* n4 = (const float4*)nrm;
        const uint4* wp = W1p + (size_t)kh * 64 * 512 + n;
        float acd = 0.f;
        #pragma unroll 8
        for (int kq = 0; kq < 64; ++kq) {
            uint4 qw = wp[kq * 512];
            float4 a = n4[kh * 128 + 2 * kq];
            float4 b = n4[kh * 128 + 2 * kq + 1];
            float nl[8] = {a.x, a.y, a.z, a.w, b.x, b.y, b.z, b.w};
            dot8bf(qw, nl, acd);
        }
        if (kh == 1) ph[n] = acd;
        __syncthreads();
        if (kh == 0) h1[n] = lrelu(acd + ph[n] + b1[n]);
    }
    __syncthreads();

    // ---- phase E: layer 2, neuron-per-lane (round-13 verified) ----
    {
        const int n  = tid & 255;
        const int qd = tid >> 8;
        const float4* h4 = (const float4*)h1;
        const uint4* wp = W2p + (size_t)qd * 16 * 256 + n;
        float ace = 0.f;
        #pragma unroll
        for (int kq = 0; kq < 16; ++kq) {
            uint4 qw = wp[kq * 256];
            float4 a = h4[qd * 32 + 2 * kq];
            float4 b = h4[qd * 32 + 2 * kq + 1];
            float nl[8] = {a.x, a.y, a.z, a.w, b.x, b.y, b.z, b.w};
            dot8bf(qw, nl, ace);
        }
        if (qd > 0) pe[(qd - 1) * 256 + n] = ace;
        __syncthreads();
        if (qd == 0) h2[n] = lrelu(ace + pe[n] + pe[256 + n] + pe[512 + n] + b2[n]);
    }
    __syncthreads();

    // ---- phase F: layer 3 ----
    if (wv < 4) {
        const float4 wt = ((const float4*)(W3 + wv * 256))[lane];
        const float4 a = ((const float4*)h2)[lane];
        float s = wt.x*a.x + wt.y*a.y + wt.z*a.z + wt.w*a.w;
        for (int off = 32; off > 0; off >>= 1) s += __shfl_xor(s, off);
        if (lane == 0) out[row * 4 + wv] = s + b3[wv];
    }
}

extern "C" void kernel_launch(void* const* d_in, const int* in_sizes, int n_in,
                              void* d_out, int out_size, void* d_ws, size_t ws_size,
                              hipStream_t stream)
{
    const float* x  = (const float*)d_in[0];
    const float* W1 = (const float*)d_in[1];
    const float* b1 = (const float*)d_in[2];
    const float* W2 = (const float*)d_in[3];
    const float* b2 = (const float*)d_in[4];
    const float* W3 = (const float*)d_in[5];
    const float* b3 = (const float*)d_in[6];
    float* outp = (float*)d_out;
    uint4* W1p = (uint4*)d_ws;                          // 1MB (65536 uint4)
    uint4* W2p = (uint4*)((char*)d_ws + (1 << 20));     // 256KB (16384 uint4)

    hipLaunchKernelGGL(conv_kernel,  dim3(320), dim3(256),  0, stream, W1, W2, W1p, W2p);
    hipLaunchKernelGGL(fused_kernel, dim3(256), dim3(1024), 0, stream,
                       x, W1p, b1, W2p, b2, W3, b3, outp);
}

// Round 16
// 45.280 us; speedup vs baseline: 1.4603x; 1.4603x over previous
//
#include <hip/hip_runtime.h>

typedef __attribute__((ext_vector_type(8))) short bf16x8;
typedef __attribute__((ext_vector_type(16))) float f32x16;

#define LN 8192
#define SA_ROWB 4240          // bytes/shifted-copy row; 4240/16=265 ≡ 1 (mod 8) → bank spread
#define SB_OFF  33920         // B buffer starts after 8 A-rows (8*4240)
#define SMEM_BYTES 65536

__device__ __forceinline__ unsigned short f2bf(float f) {
    unsigned int u = __float_as_uint(f);
    u += 0x7fffu + ((u >> 16) & 1u);
    return (unsigned short)(u >> 16);
}
__device__ __forceinline__ float lrelu(float v) { return v > 0.f ? v : 0.01f * v; }
__device__ __forceinline__ float gldx(const float* p, int i) { return (i >= 0 && i < LN) ? p[i] : 0.f; }

// dot of 8 packed bf16 weights (uint4) with 8 f32 activations
__device__ __forceinline__ void dot8bf(uint4 q, const float* nl, float& acc) {
    acc += __uint_as_float(q.x << 16)          * nl[0];
    acc += __uint_as_float(q.x & 0xffff0000u)  * nl[1];
    acc += __uint_as_float(q.y << 16)          * nl[2];
    acc += __uint_as_float(q.y & 0xffff0000u)  * nl[3];
    acc += __uint_as_float(q.z << 16)          * nl[4];
    acc += __uint_as_float(q.z & 0xffff0000u)  * nl[5];
    acc += __uint_as_float(q.w << 16)          * nl[6];
    acc += __uint_as_float(q.w & 0xffff0000u)  * nl[7];
}
__device__ __forceinline__ uint4 pack8(float4 a, float4 b) {
    uint4 pk;
    pk.x = (unsigned)f2bf(a.x) | ((unsigned)f2bf(a.y) << 16);
    pk.y = (unsigned)f2bf(a.z) | ((unsigned)f2bf(a.w) << 16);
    pk.z = (unsigned)f2bf(b.x) | ((unsigned)f2bf(b.y) << 16);
    pk.w = (unsigned)f2bf(b.z) | ((unsigned)f2bf(b.w) << 16);
    return pk;
}

// K0: reformat W1,W2 -> k-major packed bf16.
// W1p[kqq*512 + n] (kqq=0..127) holds W1[n][8kqq..8kqq+7]; W2p[kqq*256 + n] (kqq=0..63).
__global__ __launch_bounds__(256)
void conv_kernel(const float* __restrict__ W1, const float* __restrict__ W2,
                 uint4* __restrict__ W1p, uint4* __restrict__ W2p)
{
    const int b = blockIdx.x, t = threadIdx.x;
    if (b < 256) {
        const int g = b * 256 + t;          // 65536
        const int n = g >> 7, kqq = g & 127;
        const float4* src = (const float4*)(W1 + (size_t)n * 1024 + 8 * kqq);
        W1p[kqq * 512 + n] = pack8(src[0], src[1]);
    } else {
        const int g = (b - 256) * 256 + t;  // 16384
        const int n = g >> 6, kqq = g & 63;
        const float4* src = (const float4*)(W2 + (size_t)n * 512 + 8 * kqq);
        W2p[kqq * 256 + n] = pack8(src[0], src[1]);
    }
}

// K1: fused ACF (round-10 verified math, byte-identical) + row-local MLP
// (neuron-per-lane, no shuffle reduces). == round-13 best-known (45.7us).
__global__ __launch_bounds__(1024)
void fused_kernel(const float* __restrict__ x,
                  const uint4* __restrict__ W1p, const float* __restrict__ b1,
                  const uint4* __restrict__ W2p, const float* __restrict__ b2,
                  const float* __restrict__ W3, const float* __restrict__ b3,
                  float* __restrict__ out)
{
    __shared__ __align__(16) unsigned char smem[SMEM_BYTES];
    __shared__ float red[16];

    const int tid  = threadIdx.x;
    const int row  = blockIdx.x;
    const int lane = tid & 63;
    const int wv   = tid >> 6;
    const float* xr = x + (size_t)row * LN;

    // ---------------- phase A: ACF (identical to round 10) ----------------
    const int jj = lane & 31;
    const int gp = lane >> 5;
    const int dd = lane & 7;
    const int hh = (lane >> 3) & 3;
    const int aoff_lane = dd * SA_ROWB + 64 + 16 * gp - 16 * hh;

    const int q  = wv & 3;
    const int p  = wv >> 2;
    const int T1 = p;
    const int T2 = 7 - p;
    const int s1 = 512 - 64 * p;
    const int s2 = 64 + 64 * p;

    for (int s = tid; s < 1156; s += 1024) {
        const int e0 = s * 8;
        float4 fa, fb;
        if (e0 + 7 < LN) {
            fa = *(const float4*)(xr + e0);
            fb = *(const float4*)(xr + e0 + 4);
        } else {
            fa = make_float4(gldx(xr,e0),   gldx(xr,e0+1), gldx(xr,e0+2), gldx(xr,e0+3));
            fb = make_float4(gldx(xr,e0+4), gldx(xr,e0+5), gldx(xr,e0+6), gldx(xr,e0+7));
        }
        uint4 pk = pack8(fa, fb);
        const int ph = s ^ ((s >> 3) & 7);
        *(uint4*)(smem + SB_OFF + ph * 16) = pk;
    }

    f32x16 acc1 = {}, acc2 = {};

    for (int ch = 0; ch < 4; ++ch) {
        const int tc = ch << 11;
        __syncthreads();
        if (tid < 528) {
            const int base = tc + 4 * tid - 40;
            float4 fa, fb, fc;
            if (base >= 0 && base + 11 < LN) {
                fa = *(const float4*)(xr + base);
                fb = *(const float4*)(xr + base + 4);
                fc = *(const float4*)(xr + base + 8);
            } else {
                fa = make_float4(gldx(xr,base),   gldx(xr,base+1), gldx(xr,base+2),  gldx(xr,base+3));
                fb = make_float4(gldx(xr,base+4), gldx(xr,base+5), gldx(xr,base+6),  gldx(xr,base+7));
                fc = make_float4(gldx(xr,base+8), gldx(xr,base+9), gldx(xr,base+10), gldx(xr,base+11));
            }
            unsigned short us[12];
            us[0]=f2bf(fa.x); us[1]=f2bf(fa.y); us[2]=f2bf(fa.z);  us[3]=f2bf(fa.w);
            us[4]=f2bf(fb.x); us[5]=f2bf(fb.y); us[6]=f2bf(fb.z);  us[7]=f2bf(fb.w);
            us[8]=f2bf(fc.x); us[9]=f2bf(fc.y); us[10]=f2bf(fc.z); us[11]=f2bf(fc.w);
            #pragma unroll
            for (int d = 0; d < 8; ++d) {
                unsigned long long pk = (unsigned long long)us[8-d]
                                      | ((unsigned long long)us[9-d]  << 16)
                                      | ((unsigned long long)us[10-d] << 32)
                                      | ((unsigned long long)us[11-d] << 48);
                *(unsigned long long*)(smem + d * SA_ROWB + 8 * tid) = pk;
            }
        }
        __syncthreads();

        const int c0 = ch * 128;
        int dD = s2 - c0; dD = dD < 0 ? 0 : (dD > 128 ? 128 : dD);
        int sLo = c0 > s2 ? c0 : s2;
        int sHi = (c0 + 128) < s1 ? (c0 + 128) : s1;
        int sS = sHi - sLo; if (sS < 0) sS = 0;
        const int wd0 = c0 + q * (dD >> 2),  wd1 = c0 + (q + 1) * (dD >> 2);
        const int ws0 = sLo + q * (sS >> 2), ws1 = sLo + (q + 1) * (sS >> 2);

        {
            const unsigned char* ap = smem + aoff_lane + 32 * (wd0 - c0);
            int S1 = 128 * T1 + 2 * wd0 + 4 * jj + gp;
            int S2 = 128 * T2 + 2 * wd0 + 4 * jj + gp;
            for (int mq = wd0; mq < wd1; mq += 4) {
                bf16x8 A[4], B1[4], B2[4];
                #pragma unroll
                for (int u = 0; u < 4; ++u) {
                    A[u] = *(const bf16x8*)(ap + 32 * u);
                    const int sa = S1 + 2 * u, sb = S2 + 2 * u;
                    B1[u] = *(const bf16x8*)(smem + SB_OFF + ((sa ^ ((sa >> 3) & 7)) << 4));
                    B2[u] = *(const bf16x8*)(smem + SB_OFF + ((sb ^ ((sb >> 3) & 7)) << 4));
                }
                #pragma unroll
                for (int u = 0; u < 4; ++u) {
                    acc1 = __builtin_amdgcn_mfma_f32_32x32x16_bf16(A[u], B1[u], acc1, 0, 0, 0);
                    acc2 = __builtin_amdgcn_mfma_f32_32x32x16_bf16(A[u], B2[u], acc2, 0, 0, 0);
                }
                ap += 128; S1 += 8; S2 += 8;
            }
        }
        {
            const unsigned char* ap = smem + aoff_lane + 32 * (ws0 - c0);
            int S1 = 128 * T1 + 2 * ws0 + 4 * jj + gp;
            for (int mq = ws0; mq < ws1; mq += 4) {
                bf16x8 A[4], B1[4];
                #pragma unroll
                for (int u = 0; u < 4; ++u) {
                    A[u] = *(const bf16x8*)(ap + 32 * u);
                    const int sa = S1 + 2 * u;
                    B1[u] = *(const bf16x8*)(smem + SB_OFF + ((sa ^ ((sa >> 3) & 7)) << 4));
                }
                #pragma unroll
                for (int u = 0; u < 4; ++u)
                    acc1 = __builtin_amdgcn_mfma_f32_32x32x16_bf16(A[u], B1[u], acc1, 0, 0, 0);
                ap += 128; S1 += 8;
            }
        }
    }

    __syncthreads();

    auto pwrite = [&](int T, int s, const f32x16& acc, bool add) {
        unsigned char* bp = smem + (T * 2 + s) * 4096 + jj * 128;
        #pragma unroll
        for (int rq = 0; rq < 4; ++rq) {
            const int bi = (2 * rq + gp) ^ (jj & 7);
            float4 w = make_float4(acc[4*rq], acc[4*rq+1], acc[4*rq+2], acc[4*rq+3]);
            float4* pp = (float4*)(bp + bi * 16);
            if (add) { float4 o = *pp; w.x += o.x; w.y += o.y; w.z += o.z; w.w += o.w; }
            *pp = w;
        }
    };
    if (q < 2) { pwrite(T1, q, acc1, false); pwrite(T2, q, acc2, false); }
    __syncthreads();
    if (q >= 2) { pwrite(T1, q - 2, acc1, true); pwrite(T2, q - 2, acc2, true); }
    __syncthreads();

    // LDS overlay for MLP phases (all after the barrier above)
    float* nrm = (float*)smem;                   // [0, 4096)
    float* h1  = (float*)(smem + 4096);          // [4096, 6144)
    float* h2  = (float*)(smem + 6144);          // [6144, 7168)
    float* ph  = (float*)(smem + 7168);          // [7168, 9216)   layer-1 K-half partials
    float* pe  = (float*)(smem + 9216);          // [9216, 12288)  layer-2 K-quarter partials

    // ---- phase C: pool8 + rowmax + normalize -> nrm ----
    {
        const int T  = tid >> 7;
        const int j2 = (tid >> 2) & 31;
        const int rq = tid & 3;
        const unsigned char* b0 = smem + (T * 2) * 4096 + j2 * 128;
        const int biA = (2 * rq)     ^ (j2 & 7);
        const int biB = (2 * rq + 1) ^ (j2 & 7);
        float4 s0a = *(const float4*)(b0 + biA * 16);
        float4 s0b = *(const float4*)(b0 + biB * 16);
        float4 s1a = *(const float4*)(b0 + 4096 + biA * 16);
        float4 s1b = *(const float4*)(b0 + 4096 + biB * 16);
        float v0 = s0a.x + s1a.x, v1 = s0a.y + s1a.y, v2 = s0a.z + s1a.z, v3 = s0a.w + s1a.w;
        float v4 = s0b.x + s1b.x, v5 = s0b.y + s1b.y, v6 = s0b.z + s1b.z, v7 = s0b.w + s1b.w;
        float m = fmaxf(fmaxf(fmaxf(v0, v1), fmaxf(v2, v3)), fmaxf(fmaxf(v4, v5), fmaxf(v6, v7)));

        float mx = m;
        for (int off = 32; off > 0; off >>= 1) mx = fmaxf(mx, __shfl_xor(mx, off));
        if (lane == 0) red[wv] = mx;
        __syncthreads();            // all partial-buffer reads complete before this
        float pmax = red[0];
        #pragma unroll
        for (int k = 1; k < 16; ++k) pmax = fmaxf(pmax, red[k]);
        nrm[tid] = m * (1.0f / pmax);
    }
    __syncthreads();

    // ---- phase D: layer 1, neuron-per-lane; thread = (neuron n, K-half kh) ----
    {
        const int n  = tid & 511;
        const int kh = tid >> 9;                 // 0 or 1
        const float4* n4 = (const float4*)nrm;
        const uint4* wp = W1p + (size_t)kh * 64 * 512 + n;
        float acc = 0.f;
        #pragma unroll 8
        for (int kq = 0; kq < 64; ++kq) {
            uint4 qw = wp[kq * 512];
            float4 a = n4[kh * 128 + 2 * kq];
            float4 b = n4[kh * 128 + 2 * kq + 1];
            float nl[8] = {a.x, a.y, a.z, a.w, b.x, b.y, b.z, b.w};
            dot8bf(qw, nl, acc);
        }
        if (kh == 1) ph[n] = acc;
        __syncthreads();
        if (kh == 0) h1[n] = lrelu(acc + ph[n] + b1[n]);
    }
    __syncthreads();

    // ---- phase E: layer 2, neuron-per-lane; thread = (neuron n, K-quarter qd) ----
    {
        const int n  = tid & 255;
        const int qd = tid >> 8;                 // 0..3
        const float4* h4 = (const float4*)h1;
        const uint4* wp = W2p + (size_t)qd * 16 * 256 + n;
        float acc = 0.f;
        #pragma unroll
        for (int kq = 0; kq < 16; ++kq) {
            uint4 qw = wp[kq * 256];
            float4 a = h4[qd * 32 + 2 * kq];
            float4 b = h4[qd * 32 + 2 * kq + 1];
            float nl[8] = {a.x, a.y, a.z, a.w, b.x, b.y, b.z, b.w};
            dot8bf(qw, nl, acc);
        }
        if (qd > 0) pe[(qd - 1) * 256 + n] = acc;
        __syncthreads();
        if (qd == 0) h2[n] = lrelu(acc + pe[n] + pe[256 + n] + pe[512 + n] + b2[n]);
    }
    __syncthreads();

    // ---- phase F: layer 3 ----
    if (wv < 4) {
        const float4 w = ((const float4*)(W3 + wv * 256))[lane];
        const float4 a = ((const float4*)h2)[lane];
        float s = w.x*a.x + w.y*a.y + w.z*a.z + w.w*a.w;
        for (int off = 32; off > 0; off >>= 1) s += __shfl_xor(s, off);
        if (lane == 0) out[row * 4 + wv] = s + b3[wv];
    }
}

extern "C" void kernel_launch(void* const* d_in, const int* in_sizes, int n_in,
                              void* d_out, int out_size, void* d_ws, size_t ws_size,
                              hipStream_t stream)
{
    const float* x  = (const float*)d_in[0];
    const float* W1 = (const float*)d_in[1];
    const float* b1 = (const float*)d_in[2];
    const float* W2 = (const float*)d_in[3];
    const float* b2 = (const float*)d_in[4];
    const float* W3 = (const float*)d_in[5];
    const float* b3 = (const float*)d_in[6];
    float* outp = (float*)d_out;
    uint4* W1p = (uint4*)d_ws;                          // 1MB (65536 uint4)
    uint4* W2p = (uint4*)((char*)d_ws + (1 << 20));     // 256KB (16384 uint4)

    hipLaunchKernelGGL(conv_kernel,  dim3(320), dim3(256),  0, stream, W1, W2, W1p, W2p);
    hipLaunchKernelGGL(fused_kernel, dim3(256), dim3(1024), 0, stream,
                       x, W1p, b1, W2p, b2, W3, b3, outp);
}